// Round 6
// baseline (513.617 us; speedup 1.0000x reference)
//
#include <hip/hip_runtime.h>
#include <stdint.h>

#define BATCH 4
#define HEADS 16
#define SEQ   2048
#define DIM   128
#define QROWS 256   // per block: 8 waves, each owns rows qb+16w (h=0) and qb+128+16w (h=1)
#define BK    64
#define KT_TILES (SEQ / BK)   // 32

typedef short short8 __attribute__((ext_vector_type(8)));
typedef float floatx4 __attribute__((ext_vector_type(4)));

// 1/sqrt(128) * log2(e): softmax in base-2 domain
#define QK_SCALE_LOG2E 0.1274750709470246f

static __device__ __forceinline__ ushort f2bf_rn(float f) {
    union { float f; uint32_t u; } x; x.f = f;
    return (ushort)((x.u + 0x8000u) >> 16);
}
static __device__ __forceinline__ uint32_t pack_bf16x2(float f0, float f1) {
    union { float f; uint32_t u; } a, b; a.f = f0; b.f = f1;
    return __builtin_amdgcn_perm(b.u + 0x8000u, a.u + 0x8000u, 0x07060302u);
}

#define GLOAD_LDS16(gsrc, ldst) \
    __builtin_amdgcn_global_load_lds( \
        (const __attribute__((address_space(1))) uint32_t*)(gsrc), \
        (__attribute__((address_space(3))) uint32_t*)(ldst), 16, 0, 0)

// ============================================================================
// Pass 1: K,V -> bf16 MFMA-fragment blobs via LDS transpose.
// One block per (bh, kt). All global traffic fully coalesced.
// Blob unit per (bh, kt): 16 groups x 64 lanes x 8 ush = 16 KB:
//   K group g=c*4+kk, lane, j:  K[kt*64 + c*16 + l15][kk*32 + q4*8 + j]
//   V group g=t*2+kc, lane, j:  V[kt*64 + kc*32 + q4*8 + j][t*16 + l15]
// ============================================================================
__global__ __launch_bounds__(256)
void convert_kv(const float* __restrict__ K, const float* __restrict__ V,
                ushort* __restrict__ Kb, ushort* __restrict__ Vb)
{
    const int bh = blockIdx.x >> 5;
    const int kt = blockIdx.x & 31;
    __shared__ ushort lds[64][130];
    const int tid  = threadIdx.x;
    const int rr   = tid >> 2;          // row 0..63 (4 threads per row)
    const int c4   = (tid & 3) * 4;     // float4 slot within each 64B segment
    const int w    = tid >> 6;
    const int lane = tid & 63;
    const int l15  = lane & 15, q4 = lane >> 4;
    const size_t tb = (size_t)(bh * KT_TILES + kt) * (16 * 512);
    const size_t rowbase = ((size_t)bh * SEQ + kt * 64 + rr) * DIM;

    // ---- K tile -> LDS (bf16) ----
    {
        const float* src = K + rowbase;
        #pragma unroll
        for (int i = 0; i < 8; ++i) {
            float4 f = *(const float4*)(src + c4 + i * 16);
            *(uint32_t*)&lds[rr][c4 + i * 16]     = pack_bf16x2(f.x, f.y);
            *(uint32_t*)&lds[rr][c4 + i * 16 + 2] = pack_bf16x2(f.z, f.w);
        }
    }
    __syncthreads();
    // ---- emit K blob: row-contiguous 8-ushort reads ----
    #pragma unroll
    for (int p = 0; p < 4; ++p) {
        const int g = p * 4 + w;
        const ushort* lp = &lds[(g >> 2) * 16 + l15][(g & 3) * 32 + q4 * 8];
        union { short8 s; uint32_t u[4]; } o;
        #pragma unroll
        for (int i = 0; i < 4; ++i) o.u[i] = *(const uint32_t*)(lp + i * 2);
        *(short8*)(Kb + tb + (size_t)g * 512 + lane * 8) = o.s;
    }
    __syncthreads();
    // ---- V tile -> LDS (bf16) ----
    {
        const float* src = V + rowbase;
        #pragma unroll
        for (int i = 0; i < 8; ++i) {
            float4 f = *(const float4*)(src + c4 + i * 16);
            *(uint32_t*)&lds[rr][c4 + i * 16]     = pack_bf16x2(f.x, f.y);
            *(uint32_t*)&lds[rr][c4 + i * 16 + 2] = pack_bf16x2(f.z, f.w);
        }
    }
    __syncthreads();
    // ---- emit V blob: column reads (the transpose) happen in LDS, not HBM ----
    #pragma unroll
    for (int p = 0; p < 4; ++p) {
        const int g = p * 4 + w;
        const int r0 = (g & 1) * 32 + q4 * 8;
        const int c  = (g >> 1) * 16 + l15;
        union { short8 s; ushort e[8]; } o;
        #pragma unroll
        for (int j = 0; j < 8; ++j) o.e[j] = lds[r0 + j][c];
        *(short8*)(Vb + tb + (size_t)g * 512 + lane * 8) = o.s;
    }
}

// ============================================================================
// Pass 2: flash attention — R1/R5's PROVEN double-buffered schedule (one
// barrier per k-tile; stage both K,V of tile kt+1 into buf^1 at iteration
// top; the end-of-iteration __syncthreads drains the DMA). Single-buffer
// split-barrier variants are retired (R3/R4: deterministic absmax 1.375).
//
// R6 change: 8 waves / QROWS=256 per block (was 4 / 128). LDS 80KB ->
// 2 blocks/CU = 16 waves/CU (was 8), same schedule, same per-wave softmax
// cost, half the staging traffic per q-row. launch_bounds(512,2) keeps the
// VGPR cap at 256 so the allocator stays at its natural ~100 (R2 lesson:
// never force the allocator below natural pressure -> 1.1GB scratch spill).
// With QROWS=256, h=1 is no longer always active -> act[] guards on both h
// (barriers remain outside all guards: inactive waves still sync).
// ============================================================================
__global__ __launch_bounds__(512, 2)
void fa_fwd(const float* __restrict__ Q, const ushort* __restrict__ Kb,
            const ushort* __restrict__ Vb, float* __restrict__ O)
{
    const int qt = gridDim.x - 1 - blockIdx.x;   // heavy q-tiles first
    const int qb = qt * QROWS;
    const int bh = blockIdx.y;
    const size_t hb = (size_t)bh * SEQ * DIM;

    const int tid  = threadIdx.x;
    const int w    = tid >> 6;                   // 0..7
    const int lane = tid & 63;
    const int l15  = lane & 15;
    const int q4   = lane >> 4;

    __shared__ ushort kblob[2][16 * 64 * 8];    // 32 KB
    __shared__ ushort vblob[2][16 * 64 * 8];    // 32 KB
    __shared__ ushort pblob[8][2][64 * 8];      // 16 KB: [wave][kc], shared across h

    const int row0[2] = { qb + w * 16, qb + QROWS / 2 + w * 16 };

    // ---- Q fragments (A-layout) converted from fp32 (same rounding as blobs)
    short8 qf[2][4];
    #pragma unroll
    for (int h = 0; h < 2; ++h) {
        const float* qp = Q + hb + (size_t)(row0[h] + l15) * DIM + q4 * 8;
        #pragma unroll
        for (int kk = 0; kk < 4; ++kk) {
            float4 a = *(const float4*)(qp + kk * 32);
            float4 b = *(const float4*)(qp + kk * 32 + 4);
            union { short8 s; uint32_t u[4]; } u_;
            u_.u[0] = pack_bf16x2(a.x, a.y);
            u_.u[1] = pack_bf16x2(a.z, a.w);
            u_.u[2] = pack_bf16x2(b.x, b.y);
            u_.u[3] = pack_bf16x2(b.z, b.w);
            qf[h][kk] = u_.s;
        }
    }

    floatx4 o_acc[2][8];
    float m_i[2][4], l_i[2][4];
    #pragma unroll
    for (int h = 0; h < 2; ++h) {
        #pragma unroll
        for (int t = 0; t < 8; ++t) o_acc[h][t] = (floatx4){0.f, 0.f, 0.f, 0.f};
        #pragma unroll
        for (int r = 0; r < 4; ++r) { m_i[h][r] = -1e38f; l_i[h][r] = 0.f; }
    }

    // ---- async DMA staging: 2 K-groups + 2 V-groups per wave
    auto stage = [&](int kt, int buf) {
        const size_t tb = ((size_t)(bh * KT_TILES + kt)) * (16 * 512);
        #pragma unroll
        for (int p = 0; p < 2; ++p) {
            const int g = p * 8 + w;
            GLOAD_LDS16(Kb + tb + g * 512 + lane * 8, &kblob[buf][g * 512]);
            GLOAD_LDS16(Vb + tb + g * 512 + lane * 8, &vblob[buf][g * 512]);
        }
    };

    stage(0, 0);
    __syncthreads();

    const int ktend = (qb + QROWS) / BK;
    int buf = 0;
    for (int kt = 0; kt < ktend; ++kt) {
        const int kb = kt * BK;
        const bool more = (kt + 1) < ktend;
        if (more) stage(kt + 1, buf ^ 1);       // DMA hidden under compute

        const bool act[2] = { kb <= row0[0] + 15, kb <= row0[1] + 15 };
        const bool anyact = act[0] | act[1];

        // ---- QK^T: 4 col-chunks x k=128; K-frags shared across h
        floatx4 sc[2][4];
        #pragma unroll
        for (int h = 0; h < 2; ++h)
            #pragma unroll
            for (int c = 0; c < 4; ++c) sc[h][c] = (floatx4){0.f,0.f,0.f,0.f};
        if (anyact) {
            __builtin_amdgcn_s_setprio(1);
            #pragma unroll
            for (int kk = 0; kk < 4; ++kk) {
                #pragma unroll
                for (int c = 0; c < 4; ++c) {
                    short8 b = *(const short8*)(&kblob[buf][((c * 4 + kk) * 64 + lane) * 8]);
                    if (act[0]) sc[0][c] = __builtin_amdgcn_mfma_f32_16x16x32_bf16(qf[0][kk], b, sc[0][c], 0, 0, 0);
                    if (act[1]) sc[1][c] = __builtin_amdgcn_mfma_f32_16x16x32_bf16(qf[1][kk], b, sc[1][c], 0, 0, 0);
                }
            }
            __builtin_amdgcn_s_setprio(0);
        }

        // ---- online softmax (base-2) + P A-frag build, h sequential (shared pblob)
        short8 pf[2][2];
        #pragma unroll
        for (int h = 0; h < 2; ++h) {
            if (!act[h]) continue;
            const bool full = (kb + BK - 1) <= row0[h];  // tile entirely unmasked
            float mx[4];
            #pragma unroll
            for (int r = 0; r < 4; ++r) {
                const int rg = row0[h] + q4 * 4 + r;
                float m = -1e38f;
                #pragma unroll
                for (int c = 0; c < 4; ++c) {
                    float a = sc[h][c][r] * QK_SCALE_LOG2E;
                    if (!full) a = (kb + c * 16 + l15 <= rg) ? a : -1e38f;
                    sc[h][c][r] = a;
                    m = fmaxf(m, a);
                }
                mx[r] = m;
            }
            #pragma unroll
            for (int r = 0; r < 4; ++r) {
                float v = mx[r];
                v = fmaxf(v, __shfl_xor(v, 1));
                v = fmaxf(v, __shfl_xor(v, 2));
                v = fmaxf(v, __shfl_xor(v, 4));
                v = fmaxf(v, __shfl_xor(v, 8));
                mx[r] = v;
            }
            // T13 defer-rescale: keep old max unless it grew by >8 (base-2 ->
            // P bounded by 2^8; power-of-2 scaling exact). First tile:
            // m_i=-1e38 -> branch taken, alpha=0 zeroes l_i/o_acc (correct).
            float need = mx[0] - m_i[h][0];
            #pragma unroll
            for (int r = 1; r < 4; ++r) need = fmaxf(need, mx[r] - m_i[h][r]);
            if (!__all(need <= 8.0f)) {
                float alpha[4];
                #pragma unroll
                for (int r = 0; r < 4; ++r) {
                    const float mnew = fmaxf(m_i[h][r], mx[r]);
                    alpha[r] = __builtin_amdgcn_exp2f(m_i[h][r] - mnew);
                    m_i[h][r] = mnew;
                    l_i[h][r] *= alpha[r];
                }
                #pragma unroll
                for (int t = 0; t < 8; ++t)
                    #pragma unroll
                    for (int r = 0; r < 4; ++r)
                        o_acc[h][t][r] *= alpha[r];
            }
            float rsum[4];
            #pragma unroll
            for (int r = 0; r < 4; ++r) {
                float s = 0.f;
                #pragma unroll
                for (int c = 0; c < 4; ++c) {
                    const float p = __builtin_amdgcn_exp2f(sc[h][c][r] - m_i[h][r]);
                    sc[h][c][r] = p;
                    s += p;
                }
                rsum[r] = s;
            }
            #pragma unroll
            for (int r = 0; r < 4; ++r) {
                float v = rsum[r];
                v += __shfl_xor(v, 1);
                v += __shfl_xor(v, 2);
                v += __shfl_xor(v, 4);
                v += __shfl_xor(v, 8);
                l_i[h][r] += v;
            }
            #pragma unroll
            for (int c = 0; c < 4; ++c) {
                ushort* pw = pblob[w][c >> 1];
                const int wo = ((c & 1) * 2 + (l15 >> 3)) * 16;
                #pragma unroll
                for (int r = 0; r < 4; ++r)
                    pw[(wo + q4 * 4 + r) * 8 + (l15 & 7)] = f2bf_rn(sc[h][c][r]);
            }
            asm volatile("s_waitcnt lgkmcnt(0)" ::: "memory");
            pf[h][0] = *(const short8*)(&pblob[w][0][lane * 8]);
            pf[h][1] = *(const short8*)(&pblob[w][1][lane * 8]);
        }

        // ---- PV: V-frags shared across h
        if (anyact) {
            __builtin_amdgcn_s_setprio(1);
            #pragma unroll
            for (int t = 0; t < 8; ++t) {
                #pragma unroll
                for (int kc = 0; kc < 2; ++kc) {
                    short8 vf = *(const short8*)(&vblob[buf][((t * 2 + kc) * 64 + lane) * 8]);
                    if (act[0]) o_acc[0][t] = __builtin_amdgcn_mfma_f32_16x16x32_bf16(pf[0][kc], vf, o_acc[0][t], 0, 0, 0);
                    if (act[1]) o_acc[1][t] = __builtin_amdgcn_mfma_f32_16x16x32_bf16(pf[1][kc], vf, o_acc[1][t], 0, 0, 0);
                }
            }
            __builtin_amdgcn_s_setprio(0);
        }

        __syncthreads();   // drains DMA vmcnt + all LDS reads before buffer swap
        buf ^= 1;
    }

    // ---- epilogue: O = acc / l_i
    #pragma unroll
    for (int h = 0; h < 2; ++h) {
        float inv[4];
        #pragma unroll
        for (int r = 0; r < 4; ++r) inv[r] = __builtin_amdgcn_rcpf(l_i[h][r]);
        #pragma unroll
        for (int t = 0; t < 8; ++t) {
            #pragma unroll
            for (int r = 0; r < 4; ++r) {
                const int rg = row0[h] + q4 * 4 + r;
                O[hb + (size_t)rg * DIM + t * 16 + l15] = o_acc[h][t][r] * inv[r];
            }
        }
    }
}

// ============================================================================
// Fallback: used only if ws_size < 64 MB. Own geometry: 4 waves / 128 rows.
// ============================================================================
#define QROWS_FB 128
__global__ __launch_bounds__(256, 2)
void fa_fwd_fb(const float* __restrict__ Q, const float* __restrict__ K,
               const float* __restrict__ V, float* __restrict__ O)
{
    const int qt = gridDim.x - 1 - blockIdx.x;
    const int qb = qt * QROWS_FB;
    const size_t hb = (size_t)blockIdx.y * SEQ * DIM;
    const int tid  = threadIdx.x;
    const int w    = tid >> 6;
    const int lane = tid & 63;
    const int l15  = lane & 15;
    const int q4   = lane >> 4;

    __shared__ ushort kblob[2][16 * 64 * 8];
    __shared__ ushort vblob[2][16 * 64 * 8];
    __shared__ ushort pblob[4][2][64 * 8];

    const int row0[2] = { qb + w * 16, qb + 64 + w * 16 };
    short8 qf[2][4];
    #pragma unroll
    for (int h = 0; h < 2; ++h) {
        const float* qp = Q + hb + (size_t)(row0[h] + l15) * DIM + q4 * 8;
        #pragma unroll
        for (int kk = 0; kk < 4; ++kk) {
            float4 a = *(const float4*)(qp + kk * 32);
            float4 b = *(const float4*)(qp + kk * 32 + 4);
            union { short8 s; uint32_t u[4]; } u_;
            u_.u[0] = pack_bf16x2(a.x, a.y);
            u_.u[1] = pack_bf16x2(a.z, a.w);
            u_.u[2] = pack_bf16x2(b.x, b.y);
            u_.u[3] = pack_bf16x2(b.z, b.w);
            qf[h][kk] = u_.s;
        }
    }
    floatx4 o_acc[2][8];
    float m_i[2][4], l_i[2][4];
    #pragma unroll
    for (int h = 0; h < 2; ++h) {
        #pragma unroll
        for (int t = 0; t < 8; ++t) o_acc[h][t] = (floatx4){0.f, 0.f, 0.f, 0.f};
        #pragma unroll
        for (int r = 0; r < 4; ++r) { m_i[h][r] = -1e38f; l_i[h][r] = 0.f; }
    }
    float4 kr[4][2];
    float  vr[4][8];
    auto issue_k = [&](int kb) {
        #pragma unroll
        for (int p = 0; p < 4; ++p) {
            const int g = p * 4 + w;
            const float* ks = K + hb + (size_t)(kb + (g >> 2) * 16 + l15) * DIM + (g & 3) * 32 + q4 * 8;
            kr[p][0] = *(const float4*)ks;
            kr[p][1] = *(const float4*)(ks + 4);
        }
    };
    auto commit_k = [&](int buf) {
        #pragma unroll
        for (int p = 0; p < 4; ++p) {
            const int g = p * 4 + w;
            union { short8 s; uint32_t u[4]; } u_;
            u_.u[0] = pack_bf16x2(kr[p][0].x, kr[p][0].y);
            u_.u[1] = pack_bf16x2(kr[p][0].z, kr[p][0].w);
            u_.u[2] = pack_bf16x2(kr[p][1].x, kr[p][1].y);
            u_.u[3] = pack_bf16x2(kr[p][1].z, kr[p][1].w);
            *(short8*)(&kblob[buf][(g * 64 + lane) * 8]) = u_.s;
        }
    };
    auto issue_v = [&](int kb) {
        #pragma unroll
        for (int p = 0; p < 4; ++p) {
            const int g = p * 4 + w;
            const float* vs = V + hb + (size_t)(kb + (g & 1) * 32 + q4 * 8) * DIM + (g >> 1) * 16 + l15;
            #pragma unroll
            for (int j = 0; j < 8; ++j) vr[p][j] = vs[j * DIM];
        }
    };
    auto commit_v = [&](int buf) {
        #pragma unroll
        for (int p = 0; p < 4; ++p) {
            const int g = p * 4 + w;
            union { short8 s; uint32_t u[4]; } u_;
            u_.u[0] = pack_bf16x2(vr[p][0], vr[p][1]);
            u_.u[1] = pack_bf16x2(vr[p][2], vr[p][3]);
            u_.u[2] = pack_bf16x2(vr[p][4], vr[p][5]);
            u_.u[3] = pack_bf16x2(vr[p][6], vr[p][7]);
            *(short8*)(&vblob[buf][(g * 64 + lane) * 8]) = u_.s;
        }
    };
    issue_k(0); commit_k(0);
    issue_v(0); commit_v(0);
    __syncthreads();
    const int kend = qb + QROWS_FB;
    int buf = 0;
    for (int kb = 0; kb < kend; kb += BK) {
        const bool more = (kb + BK) < kend;
        if (more) issue_k(kb + BK);
        const bool act0 = kb <= row0[0] + 15;
        floatx4 sc[2][4];
        #pragma unroll
        for (int h = 0; h < 2; ++h)
            #pragma unroll
            for (int c = 0; c < 4; ++c) sc[h][c] = (floatx4){0.f,0.f,0.f,0.f};
        #pragma unroll
        for (int kk = 0; kk < 4; ++kk) {
            #pragma unroll
            for (int c = 0; c < 4; ++c) {
                short8 b = *(const short8*)(&kblob[buf][((c * 4 + kk) * 64 + lane) * 8]);
                if (act0) sc[0][c] = __builtin_amdgcn_mfma_f32_16x16x32_bf16(qf[0][kk], b, sc[0][c], 0, 0, 0);
                sc[1][c] = __builtin_amdgcn_mfma_f32_16x16x32_bf16(qf[1][kk], b, sc[1][c], 0, 0, 0);
            }
        }
        if (more) { commit_k(buf ^ 1); issue_v(kb + BK); }
        short8 pf[2][2];
        #pragma unroll
        for (int h = 0; h < 2; ++h) {
            if (h == 0 && !act0) continue;
            float mx[4];
            #pragma unroll
            for (int r = 0; r < 4; ++r) {
                const int rg = row0[h] + q4 * 4 + r;
                float m = -1e38f;
                #pragma unroll
                for (int c = 0; c < 4; ++c) {
                    float a = sc[h][c][r] * QK_SCALE_LOG2E;
                    a = (kb + c * 16 + l15 <= rg) ? a : -1e38f;
                    sc[h][c][r] = a;
                    m = fmaxf(m, a);
                }
                mx[r] = m;
            }
            #pragma unroll
            for (int r = 0; r < 4; ++r) {
                float v = mx[r];
                v = fmaxf(v, __shfl_xor(v, 1));
                v = fmaxf(v, __shfl_xor(v, 2));
                v = fmaxf(v, __shfl_xor(v, 4));
                v = fmaxf(v, __shfl_xor(v, 8));
                mx[r] = v;
            }
            float alpha[4], rsum[4];
            #pragma unroll
            for (int r = 0; r < 4; ++r) {
                const float mnew = fmaxf(m_i[h][r], mx[r]);
                alpha[r] = __builtin_amdgcn_exp2f(m_i[h][r] - mnew);
                m_i[h][r] = mnew;
                float s = 0.f;
                #pragma unroll
                for (int c = 0; c < 4; ++c) {
                    const float p = __builtin_amdgcn_exp2f(sc[h][c][r] - mnew);
                    sc[h][c][r] = p;
                    s += p;
                }
                rsum[r] = s;
            }
            #pragma unroll
            for (int r = 0; r < 4; ++r) {
                float v = rsum[r];
                v += __shfl_xor(v, 1);
                v += __shfl_xor(v, 2);
                v += __shfl_xor(v, 4);
                v += __shfl_xor(v, 8);
                l_i[h][r] = l_i[h][r] * alpha[r] + v;
            }
            #pragma unroll
            for (int c = 0; c < 4; ++c) {
                ushort* pw = pblob[w][c >> 1];
                const int wo = ((c & 1) * 2 + (l15 >> 3)) * 16;
                #pragma unroll
                for (int r = 0; r < 4; ++r)
                    pw[(wo + q4 * 4 + r) * 8 + (l15 & 7)] = f2bf_rn(sc[h][c][r]);
            }
            asm volatile("s_waitcnt lgkmcnt(0)" ::: "memory");
            pf[h][0] = *(const short8*)(&pblob[w][0][lane * 8]);
            pf[h][1] = *(const short8*)(&pblob[w][1][lane * 8]);
            #pragma unroll
            for (int t = 0; t < 8; ++t)
                #pragma unroll
                for (int r = 0; r < 4; ++r)
                    o_acc[h][t][r] *= alpha[r];
        }
        #pragma unroll
        for (int t = 0; t < 8; ++t) {
            #pragma unroll
            for (int kc = 0; kc < 2; ++kc) {
                short8 vf = *(const short8*)(&vblob[buf][((t * 2 + kc) * 64 + lane) * 8]);
                if (act0) o_acc[0][t] = __builtin_amdgcn_mfma_f32_16x16x32_bf16(pf[0][kc], vf, o_acc[0][t], 0, 0, 0);
                o_acc[1][t] = __builtin_amdgcn_mfma_f32_16x16x32_bf16(pf[1][kc], vf, o_acc[1][t], 0, 0, 0);
            }
        }
        if (more) commit_v(buf ^ 1);
        __syncthreads();
        buf ^= 1;
    }
    #pragma unroll
    for (int h = 0; h < 2; ++h) {
        float inv[4];
        #pragma unroll
        for (int r = 0; r < 4; ++r) inv[r] = __builtin_amdgcn_rcpf(l_i[h][r]);
        #pragma unroll
        for (int t = 0; t < 8; ++t) {
            #pragma unroll
            for (int r = 0; r < 4; ++r) {
                const int rg = row0[h] + q4 * 4 + r;
                O[hb + (size_t)rg * DIM + t * 16 + l15] = o_acc[h][t][r] * inv[r];
            }
        }
    }
}

extern "C" void kernel_launch(void* const* d_in, const int* in_sizes, int n_in,
                              void* d_out, int out_size, void* d_ws, size_t ws_size,
                              hipStream_t stream) {
    const float* q = (const float*)d_in[0];
    const float* k = (const float*)d_in[1];
    const float* v = (const float*)d_in[2];
    float* o = (float*)d_out;

    const size_t BLOB_BYTES = (size_t)BATCH * HEADS * SEQ * DIM * 2;  // 32 MB each
    if (ws_size >= 2 * BLOB_BYTES) {
        ushort* Kb = (ushort*)d_ws;
        ushort* Vb = (ushort*)((char*)d_ws + BLOB_BYTES);
        convert_kv<<<dim3(BATCH * HEADS * KT_TILES), dim3(256), 0, stream>>>(k, v, Kb, Vb);
        dim3 grid(SEQ / QROWS, BATCH * HEADS);
        fa_fwd<<<grid, dim3(512), 0, stream>>>(q, Kb, Vb, o);
    } else {
        dim3 grid(SEQ / QROWS_FB, BATCH * HEADS);
        fa_fwd_fb<<<grid, dim3(256), 0, stream>>>(q, k, v, o);
    }
}

// Round 9
// 426.040 us; speedup vs baseline: 1.2056x; 1.2056x over previous
//
#include <hip/hip_runtime.h>
#include <stdint.h>

#define BATCH 4
#define HEADS 16
#define SEQ   2048
#define DIM   128
#define QROWS 128   // per block: 4 waves, each owns rows qb+16w (h=0) and qb+64+16w (h=1)
#define BK    64
#define KT_TILES (SEQ / BK)   // 32
#define PROW  80    // pblob row stride (ushorts): 160B, 16B-aligned, ~4-way banks

typedef short short8 __attribute__((ext_vector_type(8)));
typedef float floatx4 __attribute__((ext_vector_type(4)));

// 1/sqrt(128) * log2(e): softmax in base-2 domain
#define QK_SCALE_LOG2E 0.1274750709470246f

static __device__ __forceinline__ uint32_t pack_bf16x2(float f0, float f1) {
    union { float f; uint32_t u; } a, b; a.f = f0; b.f = f1;
    return __builtin_amdgcn_perm(b.u + 0x8000u, a.u + 0x8000u, 0x07060302u);
}
static __device__ __forceinline__ ushort f2bf_rn(float f) {
    union { float f; uint32_t u; } x; x.f = f;
    return (ushort)((x.u + 0x8000u) >> 16);
}

#define GLOAD_LDS16(gsrc, ldst) \
    __builtin_amdgcn_global_load_lds( \
        (const __attribute__((address_space(1))) uint32_t*)(gsrc), \
        (__attribute__((address_space(3))) uint32_t*)(ldst), 16, 0, 0)

// ============================================================================
// Pass 1: K,V -> bf16 MFMA-fragment blobs via LDS transpose. (unchanged, green)
// Blob unit per (bh, kt): 16 groups x 64 lanes x 8 ush = 16 KB:
//   K group g=c*4+kk, lane, j:  K[kt*64 + c*16 + l15][kk*32 + q4*8 + j]
//   V group g=t*2+kc, lane, j:  V[kt*64 + kc*32 + q4*8 + j][t*16 + l15]
// ============================================================================
__global__ __launch_bounds__(256)
void convert_kv(const float* __restrict__ K, const float* __restrict__ V,
                ushort* __restrict__ Kb, ushort* __restrict__ Vb)
{
    const int bh = blockIdx.x >> 5;
    const int kt = blockIdx.x & 31;
    __shared__ ushort lds[64][130];
    const int tid  = threadIdx.x;
    const int rr   = tid >> 2;
    const int c4   = (tid & 3) * 4;
    const int w    = tid >> 6;
    const int lane = tid & 63;
    const int l15  = lane & 15, q4 = lane >> 4;
    const size_t tb = (size_t)(bh * KT_TILES + kt) * (16 * 512);
    const size_t rowbase = ((size_t)bh * SEQ + kt * 64 + rr) * DIM;

    {
        const float* src = K + rowbase;
        #pragma unroll
        for (int i = 0; i < 8; ++i) {
            float4 f = *(const float4*)(src + c4 + i * 16);
            *(uint32_t*)&lds[rr][c4 + i * 16]     = pack_bf16x2(f.x, f.y);
            *(uint32_t*)&lds[rr][c4 + i * 16 + 2] = pack_bf16x2(f.z, f.w);
        }
    }
    __syncthreads();
    #pragma unroll
    for (int p = 0; p < 4; ++p) {
        const int g = p * 4 + w;
        const ushort* lp = &lds[(g >> 2) * 16 + l15][(g & 3) * 32 + q4 * 8];
        union { short8 s; uint32_t u[4]; } o;
        #pragma unroll
        for (int i = 0; i < 4; ++i) o.u[i] = *(const uint32_t*)(lp + i * 2);
        *(short8*)(Kb + tb + (size_t)g * 512 + lane * 8) = o.s;
    }
    __syncthreads();
    {
        const float* src = V + rowbase;
        #pragma unroll
        for (int i = 0; i < 8; ++i) {
            float4 f = *(const float4*)(src + c4 + i * 16);
            *(uint32_t*)&lds[rr][c4 + i * 16]     = pack_bf16x2(f.x, f.y);
            *(uint32_t*)&lds[rr][c4 + i * 16 + 2] = pack_bf16x2(f.z, f.w);
        }
    }
    __syncthreads();
    #pragma unroll
    for (int p = 0; p < 4; ++p) {
        const int g = p * 4 + w;
        const int r0 = (g & 1) * 32 + q4 * 8;
        const int c  = (g >> 1) * 16 + l15;
        union { short8 s; ushort e[8]; } o;
        #pragma unroll
        for (int j = 0; j < 8; ++j) o.e[j] = lds[r0 + j][c];
        *(short8*)(Vb + tb + (size_t)g * 512 + lane * 8) = o.s;
    }
}

// ============================================================================
// Pass 2: flash attention — R1's PROVEN dbuf schedule. Swapped QK^T (mfma(K,Q))
// so each lane owns ONE q-row: sc[h][c][r] = S[row0+l15][kb + c*16 + q4*4 + r].
// Softmax fully per-lane: local max/sum over 16 regs + 2 shfl_xor(16,32);
// scalar m_i/l_i. T13 defer-rescale + full-tile mask skip (green in R5).
//
// P -> A-frag transpose: LDS round-trip (the mechanism green in R0/R1/R5;
// the R7/R8 shfl-transpose is RETIRED after 2 failures):
//   write  pw[q=l15][k=c*16+q4*4+r]  (16 u16 scatter)
//   lgkmcnt(0)
//   read   short8 @ pw[l15][kc*32+q4*8]  == P[q=l15][kc*32+q4*8+j]  (A-layout)
// Row stride PROW=80 ush (160B): keeps b128 reads 16B-aligned, ~4-way banks.
// ============================================================================
__global__ __launch_bounds__(256, 2)
void fa_fwd(const float* __restrict__ Q, const ushort* __restrict__ Kb,
            const ushort* __restrict__ Vb, float* __restrict__ O)
{
    const int qt = gridDim.x - 1 - blockIdx.x;   // heavy q-tiles first
    const int qb = qt * QROWS;
    const int bh = blockIdx.y;
    const size_t hb = (size_t)bh * SEQ * DIM;

    const int tid  = threadIdx.x;
    const int w    = tid >> 6;
    const int lane = tid & 63;
    const int l15  = lane & 15;
    const int q4   = lane >> 4;

    __shared__ ushort kblob[2][16 * 64 * 8];    // 32 KB
    __shared__ ushort vblob[2][16 * 64 * 8];    // 32 KB
    __shared__ ushort pblob[4][16 * PROW];      // 10 KB: per-wave P rows

    const int row0[2] = { qb + w * 16, qb + 64 + w * 16 };

    // ---- Q fragments (lane layout serves as B-operand for swapped QK^T)
    short8 qf[2][4];
    #pragma unroll
    for (int h = 0; h < 2; ++h) {
        const float* qp = Q + hb + (size_t)(row0[h] + l15) * DIM + q4 * 8;
        #pragma unroll
        for (int kk = 0; kk < 4; ++kk) {
            float4 a = *(const float4*)(qp + kk * 32);
            float4 b = *(const float4*)(qp + kk * 32 + 4);
            union { short8 s; uint32_t u[4]; } u_;
            u_.u[0] = pack_bf16x2(a.x, a.y);
            u_.u[1] = pack_bf16x2(a.z, a.w);
            u_.u[2] = pack_bf16x2(b.x, b.y);
            u_.u[3] = pack_bf16x2(b.z, b.w);
            qf[h][kk] = u_.s;
        }
    }

    floatx4 o_acc[2][8];
    float m_i[2], l_i[2];
    #pragma unroll
    for (int h = 0; h < 2; ++h) {
        #pragma unroll
        for (int t = 0; t < 8; ++t) o_acc[h][t] = (floatx4){0.f, 0.f, 0.f, 0.f};
        m_i[h] = -1e38f; l_i[h] = 0.f;
    }

    auto stage = [&](int kt, int buf) {
        const size_t tb = ((size_t)(bh * KT_TILES + kt)) * (16 * 512);
        #pragma unroll
        for (int p = 0; p < 4; ++p) {
            const int g = p * 4 + w;
            GLOAD_LDS16(Kb + tb + g * 512 + lane * 8, &kblob[buf][g * 512]);
            GLOAD_LDS16(Vb + tb + g * 512 + lane * 8, &vblob[buf][g * 512]);
        }
    };

    stage(0, 0);
    __syncthreads();

    const int ktend = (qb + QROWS) / BK;
    int buf = 0;
    for (int kt = 0; kt < ktend; ++kt) {
        const int kb = kt * BK;
        const bool more = (kt + 1) < ktend;
        if (more) stage(kt + 1, buf ^ 1);       // DMA hidden under compute

        const bool act0 = kb <= row0[0] + 15;   // h=1 always active for executed kb

        // ---- QK^T (SWAPPED): sc[h][c][r] = S[row0+l15][kb + c*16 + q4*4 + r]
        floatx4 sc[2][4];
        #pragma unroll
        for (int h = 0; h < 2; ++h)
            #pragma unroll
            for (int c = 0; c < 4; ++c) sc[h][c] = (floatx4){0.f,0.f,0.f,0.f};
        __builtin_amdgcn_s_setprio(1);
        #pragma unroll
        for (int kk = 0; kk < 4; ++kk) {
            #pragma unroll
            for (int c = 0; c < 4; ++c) {
                short8 b = *(const short8*)(&kblob[buf][((c * 4 + kk) * 64 + lane) * 8]);
                if (act0) sc[0][c] = __builtin_amdgcn_mfma_f32_16x16x32_bf16(b, qf[0][kk], sc[0][c], 0, 0, 0);
                sc[1][c] = __builtin_amdgcn_mfma_f32_16x16x32_bf16(b, qf[1][kk], sc[1][c], 0, 0, 0);
            }
        }
        __builtin_amdgcn_s_setprio(0);

        // ---- per-lane online softmax (base-2); P -> pblob -> A-frag
        short8 pa[2][2];   // [h][kc] A-frags for PV
        ushort* pw = &pblob[w][0];
        #pragma unroll
        for (int h = 0; h < 2; ++h) {
            if (h == 0 && !act0) continue;
            const bool full = (kb + BK - 1) <= row0[h];  // tile entirely unmasked
            const int qg = row0[h] + l15;
            float m = -1e38f;
            #pragma unroll
            for (int c = 0; c < 4; ++c)
                #pragma unroll
                for (int r = 0; r < 4; ++r) {
                    float x = sc[h][c][r] * QK_SCALE_LOG2E;
                    if (!full) x = (kb + c * 16 + q4 * 4 + r <= qg) ? x : -1e38f;
                    sc[h][c][r] = x;
                    m = fmaxf(m, x);
                }
            m = fmaxf(m, __shfl_xor(m, 16));
            m = fmaxf(m, __shfl_xor(m, 32));
            // T13 defer-rescale (wave-uniform branch; P bounded by 2^8)
            if (!__all(m - m_i[h] <= 8.0f)) {
                const float mnew = fmaxf(m_i[h], m);
                const float alpha = __builtin_amdgcn_exp2f(m_i[h] - mnew);
                m_i[h] = mnew;
                l_i[h] *= alpha;
                float ab[4];
                #pragma unroll
                for (int r = 0; r < 4; ++r) ab[r] = __shfl(alpha, q4 * 4 + r);
                #pragma unroll
                for (int t = 0; t < 8; ++t)
                    #pragma unroll
                    for (int r = 0; r < 4; ++r) o_acc[h][t][r] *= ab[r];
            }
            float s = 0.f;
            #pragma unroll
            for (int c = 0; c < 4; ++c)
                #pragma unroll
                for (int r = 0; r < 4; ++r) {
                    const float p = __builtin_amdgcn_exp2f(sc[h][c][r] - m_i[h]);
                    sc[h][c][r] = p;
                    s += p;
                }
            s += __shfl_xor(s, 16);
            s += __shfl_xor(s, 32);
            l_i[h] += s;
            // ---- P row -> pblob (q = l15, k = c*16 + q4*4 + r)
            #pragma unroll
            for (int c = 0; c < 4; ++c)
                #pragma unroll
                for (int r = 0; r < 4; ++r)
                    pw[l15 * PROW + c * 16 + q4 * 4 + r] = f2bf_rn(sc[h][c][r]);
            asm volatile("s_waitcnt lgkmcnt(0)" ::: "memory");
            pa[h][0] = *(const short8*)(&pw[l15 * PROW + q4 * 8]);
            pa[h][1] = *(const short8*)(&pw[l15 * PROW + 32 + q4 * 8]);
        }

        // ---- PV: V-frags shared across h (unchanged from green rounds)
        __builtin_amdgcn_s_setprio(1);
        #pragma unroll
        for (int t = 0; t < 8; ++t) {
            #pragma unroll
            for (int kc = 0; kc < 2; ++kc) {
                short8 vf = *(const short8*)(&vblob[buf][((t * 2 + kc) * 64 + lane) * 8]);
                if (act0) o_acc[0][t] = __builtin_amdgcn_mfma_f32_16x16x32_bf16(pa[0][kc], vf, o_acc[0][t], 0, 0, 0);
                o_acc[1][t] = __builtin_amdgcn_mfma_f32_16x16x32_bf16(pa[1][kc], vf, o_acc[1][t], 0, 0, 0);
            }
        }
        __builtin_amdgcn_s_setprio(0);

        __syncthreads();   // drains DMA vmcnt + all LDS reads before buffer swap
        buf ^= 1;
    }

    // ---- epilogue: O = acc / l_i  (l for q-row q4*4+r lives at lane q4*4+r)
    #pragma unroll
    for (int h = 0; h < 2; ++h) {
        float inv[4];
        #pragma unroll
        for (int r = 0; r < 4; ++r)
            inv[r] = __builtin_amdgcn_rcpf(__shfl(l_i[h], q4 * 4 + r));
        #pragma unroll
        for (int t = 0; t < 8; ++t) {
            #pragma unroll
            for (int r = 0; r < 4; ++r) {
                const int rg = row0[h] + q4 * 4 + r;
                O[hb + (size_t)rg * DIM + t * 16 + l15] = o_acc[h][t][r] * inv[r];
            }
        }
    }
}

// ============================================================================
// Fallback: used only if ws_size < 64 MB. (R1 lineage, proven)
// ============================================================================
#define QROWS_FB 128
__global__ __launch_bounds__(256, 2)
void fa_fwd_fb(const float* __restrict__ Q, const float* __restrict__ K,
               const float* __restrict__ V, float* __restrict__ O)
{
    const int qt = gridDim.x - 1 - blockIdx.x;
    const int qb = qt * QROWS_FB;
    const size_t hb = (size_t)blockIdx.y * SEQ * DIM;
    const int tid  = threadIdx.x;
    const int w    = tid >> 6;
    const int lane = tid & 63;
    const int l15  = lane & 15;
    const int q4   = lane >> 4;

    __shared__ ushort kblob[2][16 * 64 * 8];
    __shared__ ushort vblob[2][16 * 64 * 8];
    __shared__ ushort pblob[4][2][64 * 8];

    const int row0[2] = { qb + w * 16, qb + 64 + w * 16 };
    short8 qf[2][4];
    #pragma unroll
    for (int h = 0; h < 2; ++h) {
        const float* qp = Q + hb + (size_t)(row0[h] + l15) * DIM + q4 * 8;
        #pragma unroll
        for (int kk = 0; kk < 4; ++kk) {
            float4 a = *(const float4*)(qp + kk * 32);
            float4 b = *(const float4*)(qp + kk * 32 + 4);
            union { short8 s; uint32_t u[4]; } u_;
            u_.u[0] = pack_bf16x2(a.x, a.y);
            u_.u[1] = pack_bf16x2(a.z, a.w);
            u_.u[2] = pack_bf16x2(b.x, b.y);
            u_.u[3] = pack_bf16x2(b.z, b.w);
            qf[h][kk] = u_.s;
        }
    }
    floatx4 o_acc[2][8];
    float m_i[2][4], l_i[2][4];
    #pragma unroll
    for (int h = 0; h < 2; ++h) {
        #pragma unroll
        for (int t = 0; t < 8; ++t) o_acc[h][t] = (floatx4){0.f, 0.f, 0.f, 0.f};
        #pragma unroll
        for (int r = 0; r < 4; ++r) { m_i[h][r] = -1e38f; l_i[h][r] = 0.f; }
    }
    float4 kr[4][2];
    float  vr[4][8];
    auto issue_k = [&](int kb) {
        #pragma unroll
        for (int p = 0; p < 4; ++p) {
            const int g = p * 4 + w;
            const float* ks = K + hb + (size_t)(kb + (g >> 2) * 16 + l15) * DIM + (g & 3) * 32 + q4 * 8;
            kr[p][0] = *(const float4*)ks;
            kr[p][1] = *(const float4*)(ks + 4);
        }
    };
    auto commit_k = [&](int buf) {
        #pragma unroll
        for (int p = 0; p < 4; ++p) {
            const int g = p * 4 + w;
            union { short8 s; uint32_t u[4]; } u_;
            u_.u[0] = pack_bf16x2(kr[p][0].x, kr[p][0].y);
            u_.u[1] = pack_bf16x2(kr[p][0].z, kr[p][0].w);
            u_.u[2] = pack_bf16x2(kr[p][1].x, kr[p][1].y);
            u_.u[3] = pack_bf16x2(kr[p][1].z, kr[p][1].w);
            *(short8*)(&kblob[buf][(g * 64 + lane) * 8]) = u_.s;
        }
    };
    auto issue_v = [&](int kb) {
        #pragma unroll
        for (int p = 0; p < 4; ++p) {
            const int g = p * 4 + w;
            const float* vs = V + hb + (size_t)(kb + (g & 1) * 32 + q4 * 8) * DIM + (g >> 1) * 16 + l15;
            #pragma unroll
            for (int j = 0; j < 8; ++j) vr[p][j] = vs[j * DIM];
        }
    };
    auto commit_v = [&](int buf) {
        #pragma unroll
        for (int p = 0; p < 4; ++p) {
            const int g = p * 4 + w;
            union { short8 s; uint32_t u[4]; } u_;
            u_.u[0] = pack_bf16x2(vr[p][0], vr[p][1]);
            u_.u[1] = pack_bf16x2(vr[p][2], vr[p][3]);
            u_.u[2] = pack_bf16x2(vr[p][4], vr[p][5]);
            u_.u[3] = pack_bf16x2(vr[p][6], vr[p][7]);
            *(short8*)(&vblob[buf][(g * 64 + lane) * 8]) = u_.s;
        }
    };
    issue_k(0); commit_k(0);
    issue_v(0); commit_v(0);
    __syncthreads();
    const int kend = qb + QROWS_FB;
    int buf = 0;
    for (int kb = 0; kb < kend; kb += BK) {
        const bool more = (kb + BK) < kend;
        if (more) issue_k(kb + BK);
        const bool act0 = kb <= row0[0] + 15;
        floatx4 sc[2][4];
        #pragma unroll
        for (int h = 0; h < 2; ++h)
            #pragma unroll
            for (int c = 0; c < 4; ++c) sc[h][c] = (floatx4){0.f,0.f,0.f,0.f};
        #pragma unroll
        for (int kk = 0; kk < 4; ++kk) {
            #pragma unroll
            for (int c = 0; c < 4; ++c) {
                short8 b = *(const short8*)(&kblob[buf][((c * 4 + kk) * 64 + lane) * 8]);
                if (act0) sc[0][c] = __builtin_amdgcn_mfma_f32_16x16x32_bf16(qf[0][kk], b, sc[0][c], 0, 0, 0);
                sc[1][c] = __builtin_amdgcn_mfma_f32_16x16x32_bf16(qf[1][kk], b, sc[1][c], 0, 0, 0);
            }
        }
        if (more) { commit_k(buf ^ 1); issue_v(kb + BK); }
        short8 pf[2][2];
        #pragma unroll
        for (int h = 0; h < 2; ++h) {
            if (h == 0 && !act0) continue;
            float mx[4];
            #pragma unroll
            for (int r = 0; r < 4; ++r) {
                const int rg = row0[h] + q4 * 4 + r;
                float m = -1e38f;
                #pragma unroll
                for (int c = 0; c < 4; ++c) {
                    float a = sc[h][c][r] * QK_SCALE_LOG2E;
                    a = (kb + c * 16 + l15 <= rg) ? a : -1e38f;
                    sc[h][c][r] = a;
                    m = fmaxf(m, a);
                }
                mx[r] = m;
            }
            #pragma unroll
            for (int r = 0; r < 4; ++r) {
                float v = mx[r];
                v = fmaxf(v, __shfl_xor(v, 1));
                v = fmaxf(v, __shfl_xor(v, 2));
                v = fmaxf(v, __shfl_xor(v, 4));
                v = fmaxf(v, __shfl_xor(v, 8));
                mx[r] = v;
            }
            float alpha[4], rsum[4];
            #pragma unroll
            for (int r = 0; r < 4; ++r) {
                const float mnew = fmaxf(m_i[h][r], mx[r]);
                alpha[r] = __builtin_amdgcn_exp2f(m_i[h][r] - mnew);
                m_i[h][r] = mnew;
                float s = 0.f;
                #pragma unroll
                for (int c = 0; c < 4; ++c) {
                    const float p = __builtin_amdgcn_exp2f(sc[h][c][r] - mnew);
                    sc[h][c][r] = p;
                    s += p;
                }
                rsum[r] = s;
            }
            #pragma unroll
            for (int r = 0; r < 4; ++r) {
                float v = rsum[r];
                v += __shfl_xor(v, 1);
                v += __shfl_xor(v, 2);
                v += __shfl_xor(v, 4);
                v += __shfl_xor(v, 8);
                l_i[h][r] = l_i[h][r] * alpha[r] + v;
            }
            #pragma unroll
            for (int c = 0; c < 4; ++c) {
                ushort* pw = pblob[w][c >> 1];
                const int wo = ((c & 1) * 2 + (l15 >> 3)) * 16;
                #pragma unroll
                for (int r = 0; r < 4; ++r)
                    pw[(wo + q4 * 4 + r) * 8 + (l15 & 7)] = f2bf_rn(sc[h][c][r]);
            }
            asm volatile("s_waitcnt lgkmcnt(0)" ::: "memory");
            pf[h][0] = *(const short8*)(&pblob[w][0][lane * 8]);
            pf[h][1] = *(const short8*)(&pblob[w][1][lane * 8]);
            #pragma unroll
            for (int t = 0; t < 8; ++t)
                #pragma unroll
                for (int r = 0; r < 4; ++r)
                    o_acc[h][t][r] *= alpha[r];
        }
        #pragma unroll
        for (int t = 0; t < 8; ++t) {
            #pragma unroll
            for (int kc = 0; kc < 2; ++kc) {
                short8 vf = *(const short8*)(&vblob[buf][((t * 2 + kc) * 64 + lane) * 8]);
                if (act0) o_acc[0][t] = __builtin_amdgcn_mfma_f32_16x16x32_bf16(pf[0][kc], vf, o_acc[0][t], 0, 0, 0);
                o_acc[1][t] = __builtin_amdgcn_mfma_f32_16x16x32_bf16(pf[1][kc], vf, o_acc[1][t], 0, 0, 0);
            }
        }
        if (more) commit_v(buf ^ 1);
        __syncthreads();
        buf ^= 1;
    }
    #pragma unroll
    for (int h = 0; h < 2; ++h) {
        float inv[4];
        #pragma unroll
        for (int r = 0; r < 4; ++r) inv[r] = __builtin_amdgcn_rcpf(l_i[h][r]);
        #pragma unroll
        for (int t = 0; t < 8; ++t) {
            #pragma unroll
            for (int r = 0; r < 4; ++r) {
                const int rg = row0[h] + q4 * 4 + r;
                O[hb + (size_t)rg * DIM + t * 16 + l15] = o_acc[h][t][r] * inv[r];
            }
        }
    }
}

extern "C" void kernel_launch(void* const* d_in, const int* in_sizes, int n_in,
                              void* d_out, int out_size, void* d_ws, size_t ws_size,
                              hipStream_t stream) {
    const float* q = (const float*)d_in[0];
    const float* k = (const float*)d_in[1];
    const float* v = (const float*)d_in[2];
    float* o = (float*)d_out;

    const size_t BLOB_BYTES = (size_t)BATCH * HEADS * SEQ * DIM * 2;  // 32 MB each
    if (ws_size >= 2 * BLOB_BYTES) {
        ushort* Kb = (ushort*)d_ws;
        ushort* Vb = (ushort*)((char*)d_ws + BLOB_BYTES);
        convert_kv<<<dim3(BATCH * HEADS * KT_TILES), dim3(256), 0, stream>>>(k, v, Kb, Vb);
        dim3 grid(SEQ / QROWS, BATCH * HEADS);
        fa_fwd<<<grid, dim3(256), 0, stream>>>(q, Kb, Vb, o);
    } else {
        dim3 grid(SEQ / QROWS_FB, BATCH * HEADS);
        fa_fwd_fb<<<grid, dim3(256), 0, stream>>>(q, k, v, o);
    }
}

// Round 10
// 408.422 us; speedup vs baseline: 1.2576x; 1.0431x over previous
//
#include <hip/hip_runtime.h>
#include <stdint.h>

#define BATCH 4
#define HEADS 16
#define SEQ   2048
#define DIM   128
#define QROWS 128   // per block: 4 waves, each owns rows qb+16w (h=0) and qb+64+16w (h=1)
#define BK    64
#define KT_TILES (SEQ / BK)   // 32

typedef short short8 __attribute__((ext_vector_type(8)));
typedef float floatx4 __attribute__((ext_vector_type(4)));

// 1/sqrt(128) * log2(e): softmax in base-2 domain
#define QK_SCALE_LOG2E 0.1274750709470246f

static __device__ __forceinline__ uint32_t pack_bf16x2(float f0, float f1) {
    union { float f; uint32_t u; } a, b; a.f = f0; b.f = f1;
    return __builtin_amdgcn_perm(b.u + 0x8000u, a.u + 0x8000u, 0x07060302u);
}
static __device__ __forceinline__ ushort f2bf_rn(float f) {
    union { float f; uint32_t u; } x; x.f = f;
    return (ushort)((x.u + 0x8000u) >> 16);
}

#define GLOAD_LDS16(gsrc, ldst) \
    __builtin_amdgcn_global_load_lds( \
        (const __attribute__((address_space(1))) uint32_t*)(gsrc), \
        (__attribute__((address_space(3))) uint32_t*)(ldst), 16, 0, 0)

// ============================================================================
// Pass 1: K,V -> bf16 MFMA-fragment blobs via LDS transpose. (unchanged, green)
// Blob unit per (bh, kt): 16 groups x 64 lanes x 8 ush = 16 KB:
//   K group g=c*4+kk, lane, j:  K[kt*64 + c*16 + l15][kk*32 + q4*8 + j]
//   V group g=t*2+kc, lane, j:  V[kt*64 + kc*32 + q4*8 + j][t*16 + l15]
// ============================================================================
__global__ __launch_bounds__(256)
void convert_kv(const float* __restrict__ K, const float* __restrict__ V,
                ushort* __restrict__ Kb, ushort* __restrict__ Vb)
{
    const int bh = blockIdx.x >> 5;
    const int kt = blockIdx.x & 31;
    __shared__ ushort lds[64][130];
    const int tid  = threadIdx.x;
    const int rr   = tid >> 2;
    const int c4   = (tid & 3) * 4;
    const int w    = tid >> 6;
    const int lane = tid & 63;
    const int l15  = lane & 15, q4 = lane >> 4;
    const size_t tb = (size_t)(bh * KT_TILES + kt) * (16 * 512);
    const size_t rowbase = ((size_t)bh * SEQ + kt * 64 + rr) * DIM;

    {
        const float* src = K + rowbase;
        #pragma unroll
        for (int i = 0; i < 8; ++i) {
            float4 f = *(const float4*)(src + c4 + i * 16);
            *(uint32_t*)&lds[rr][c4 + i * 16]     = pack_bf16x2(f.x, f.y);
            *(uint32_t*)&lds[rr][c4 + i * 16 + 2] = pack_bf16x2(f.z, f.w);
        }
    }
    __syncthreads();
    #pragma unroll
    for (int p = 0; p < 4; ++p) {
        const int g = p * 4 + w;
        const ushort* lp = &lds[(g >> 2) * 16 + l15][(g & 3) * 32 + q4 * 8];
        union { short8 s; uint32_t u[4]; } o;
        #pragma unroll
        for (int i = 0; i < 4; ++i) o.u[i] = *(const uint32_t*)(lp + i * 2);
        *(short8*)(Kb + tb + (size_t)g * 512 + lane * 8) = o.s;
    }
    __syncthreads();
    {
        const float* src = V + rowbase;
        #pragma unroll
        for (int i = 0; i < 8; ++i) {
            float4 f = *(const float4*)(src + c4 + i * 16);
            *(uint32_t*)&lds[rr][c4 + i * 16]     = pack_bf16x2(f.x, f.y);
            *(uint32_t*)&lds[rr][c4 + i * 16 + 2] = pack_bf16x2(f.z, f.w);
        }
    }
    __syncthreads();
    #pragma unroll
    for (int p = 0; p < 4; ++p) {
        const int g = p * 4 + w;
        const int r0 = (g & 1) * 32 + q4 * 8;
        const int c  = (g >> 1) * 16 + l15;
        union { short8 s; ushort e[8]; } o;
        #pragma unroll
        for (int j = 0; j < 8; ++j) o.e[j] = lds[r0 + j][c];
        *(short8*)(Vb + tb + (size_t)g * 512 + lane * 8) = o.s;
    }
}

// ============================================================================
// Pass 2: flash attention — R1's PROVEN dbuf schedule. Swapped QK^T (mfma(K,Q))
// so each lane owns ONE q-row: sc[h][c][r] = S[row0+l15][kb + c*16 + q4*4 + r].
// Softmax fully per-lane (green in R9): local max/sum + 2 shfl_xor(16,32),
// scalar m_i/l_i, T13 defer-rescale, full-tile mask skip.
//
// R10 changes (softmax phase only; R9 PMC showed bank-conflict 6.5M from
// 16 scalar u16 scatter writes/h at PROW=80):
//  1. P writes packed 16xu16 -> 4x b64 (uint2) per h.
//  2. pblob XOR-swizzled, PROW=64: phys = l15*64 + (off ^ ((l15&7)<<3)),
//     granule = 8 ushorts. Same-row write/read use the same involution so
//     the logical layout round-trips; reads 2-way (free), writes <=4-way.
//  3. Per-h pblob regions + SINGLE lgkmcnt(0) drain for both h (removes one
//     full LDS drain per tile; h=1 VALU overlaps h=0 writes). Per-wave LDS
//     in-order FIFO makes next-tile WAR on pblob safe (same as R9's h=1).
// ============================================================================
__global__ __launch_bounds__(256, 2)
void fa_fwd(const float* __restrict__ Q, const ushort* __restrict__ Kb,
            const ushort* __restrict__ Vb, float* __restrict__ O)
{
    const int qt = gridDim.x - 1 - blockIdx.x;   // heavy q-tiles first
    const int qb = qt * QROWS;
    const int bh = blockIdx.y;
    const size_t hb = (size_t)bh * SEQ * DIM;

    const int tid  = threadIdx.x;
    const int w    = tid >> 6;
    const int lane = tid & 63;
    const int l15  = lane & 15;
    const int q4   = lane >> 4;

    __shared__ ushort kblob[2][16 * 64 * 8];    // 32 KB
    __shared__ ushort vblob[2][16 * 64 * 8];    // 32 KB
    __shared__ ushort pblob[4][2][16 * 64];     // 16 KB: [wave][h][row][64]

    const int row0[2] = { qb + w * 16, qb + 64 + w * 16 };
    const int swz = (l15 & 7) << 3;             // ushort-index XOR, 8-ush granule

    // ---- Q fragments (lane layout serves as B-operand for swapped QK^T)
    short8 qf[2][4];
    #pragma unroll
    for (int h = 0; h < 2; ++h) {
        const float* qp = Q + hb + (size_t)(row0[h] + l15) * DIM + q4 * 8;
        #pragma unroll
        for (int kk = 0; kk < 4; ++kk) {
            float4 a = *(const float4*)(qp + kk * 32);
            float4 b = *(const float4*)(qp + kk * 32 + 4);
            union { short8 s; uint32_t u[4]; } u_;
            u_.u[0] = pack_bf16x2(a.x, a.y);
            u_.u[1] = pack_bf16x2(a.z, a.w);
            u_.u[2] = pack_bf16x2(b.x, b.y);
            u_.u[3] = pack_bf16x2(b.z, b.w);
            qf[h][kk] = u_.s;
        }
    }

    floatx4 o_acc[2][8];
    float m_i[2], l_i[2];
    #pragma unroll
    for (int h = 0; h < 2; ++h) {
        #pragma unroll
        for (int t = 0; t < 8; ++t) o_acc[h][t] = (floatx4){0.f, 0.f, 0.f, 0.f};
        m_i[h] = -1e38f; l_i[h] = 0.f;
    }

    auto stage = [&](int kt, int buf) {
        const size_t tb = ((size_t)(bh * KT_TILES + kt)) * (16 * 512);
        #pragma unroll
        for (int p = 0; p < 4; ++p) {
            const int g = p * 4 + w;
            GLOAD_LDS16(Kb + tb + g * 512 + lane * 8, &kblob[buf][g * 512]);
            GLOAD_LDS16(Vb + tb + g * 512 + lane * 8, &vblob[buf][g * 512]);
        }
    };

    stage(0, 0);
    __syncthreads();

    const int ktend = (qb + QROWS) / BK;
    int buf = 0;
    for (int kt = 0; kt < ktend; ++kt) {
        const int kb = kt * BK;
        const bool more = (kt + 1) < ktend;
        if (more) stage(kt + 1, buf ^ 1);       // DMA hidden under compute

        const bool act0 = kb <= row0[0] + 15;   // h=1 always active for executed kb

        // ---- QK^T (SWAPPED): sc[h][c][r] = S[row0+l15][kb + c*16 + q4*4 + r]
        floatx4 sc[2][4];
        #pragma unroll
        for (int h = 0; h < 2; ++h)
            #pragma unroll
            for (int c = 0; c < 4; ++c) sc[h][c] = (floatx4){0.f,0.f,0.f,0.f};
        __builtin_amdgcn_s_setprio(1);
        #pragma unroll
        for (int kk = 0; kk < 4; ++kk) {
            #pragma unroll
            for (int c = 0; c < 4; ++c) {
                short8 b = *(const short8*)(&kblob[buf][((c * 4 + kk) * 64 + lane) * 8]);
                if (act0) sc[0][c] = __builtin_amdgcn_mfma_f32_16x16x32_bf16(b, qf[0][kk], sc[0][c], 0, 0, 0);
                sc[1][c] = __builtin_amdgcn_mfma_f32_16x16x32_bf16(b, qf[1][kk], sc[1][c], 0, 0, 0);
            }
        }
        __builtin_amdgcn_s_setprio(0);

        // ---- per-lane online softmax (base-2); both h write, ONE drain, read
        short8 pa[2][2];   // [h][kc] A-frags for PV
        #pragma unroll
        for (int h = 0; h < 2; ++h) {
            if (h == 0 && !act0) continue;
            const bool full = (kb + BK - 1) <= row0[h];  // tile entirely unmasked
            const int qg = row0[h] + l15;
            float m = -1e38f;
            #pragma unroll
            for (int c = 0; c < 4; ++c)
                #pragma unroll
                for (int r = 0; r < 4; ++r) {
                    float x = sc[h][c][r] * QK_SCALE_LOG2E;
                    if (!full) x = (kb + c * 16 + q4 * 4 + r <= qg) ? x : -1e38f;
                    sc[h][c][r] = x;
                    m = fmaxf(m, x);
                }
            m = fmaxf(m, __shfl_xor(m, 16));
            m = fmaxf(m, __shfl_xor(m, 32));
            // T13 defer-rescale (wave-uniform branch; P bounded by 2^8)
            if (!__all(m - m_i[h] <= 8.0f)) {
                const float mnew = fmaxf(m_i[h], m);
                const float alpha = __builtin_amdgcn_exp2f(m_i[h] - mnew);
                m_i[h] = mnew;
                l_i[h] *= alpha;
                float ab[4];
                #pragma unroll
                for (int r = 0; r < 4; ++r) ab[r] = __shfl(alpha, q4 * 4 + r);
                #pragma unroll
                for (int t = 0; t < 8; ++t)
                    #pragma unroll
                    for (int r = 0; r < 4; ++r) o_acc[h][t][r] *= ab[r];
            }
            float s = 0.f;
            #pragma unroll
            for (int c = 0; c < 4; ++c)
                #pragma unroll
                for (int r = 0; r < 4; ++r) {
                    const float p = __builtin_amdgcn_exp2f(sc[h][c][r] - m_i[h]);
                    sc[h][c][r] = p;
                    s += p;
                }
            s += __shfl_xor(s, 16);
            s += __shfl_xor(s, 32);
            l_i[h] += s;
            // ---- P row -> pblob, packed b64, swizzled (q=l15, k=c*16+q4*4+r)
            ushort* pw = &pblob[w][h][0];
            #pragma unroll
            for (int c = 0; c < 4; ++c) {
                uint2 u;
                u.x = pack_bf16x2(sc[h][c][0], sc[h][c][1]);
                u.y = pack_bf16x2(sc[h][c][2], sc[h][c][3]);
                const int idx = l15 * 64 + ((c * 16 + q4 * 4) ^ swz);
                *(uint2*)(&pw[idx]) = u;
            }
        }
        asm volatile("s_waitcnt lgkmcnt(0)" ::: "memory");
        #pragma unroll
        for (int h = 0; h < 2; ++h) {
            #pragma unroll
            for (int kc = 0; kc < 2; ++kc) {
                const int idx = l15 * 64 + ((kc * 32 + q4 * 8) ^ swz);
                pa[h][kc] = *(const short8*)(&pblob[w][h][idx]);
            }
        }

        // ---- PV: V-frags shared across h (unchanged from green rounds)
        __builtin_amdgcn_s_setprio(1);
        #pragma unroll
        for (int t = 0; t < 8; ++t) {
            #pragma unroll
            for (int kc = 0; kc < 2; ++kc) {
                short8 vf = *(const short8*)(&vblob[buf][((t * 2 + kc) * 64 + lane) * 8]);
                if (act0) o_acc[0][t] = __builtin_amdgcn_mfma_f32_16x16x32_bf16(pa[0][kc], vf, o_acc[0][t], 0, 0, 0);
                o_acc[1][t] = __builtin_amdgcn_mfma_f32_16x16x32_bf16(pa[1][kc], vf, o_acc[1][t], 0, 0, 0);
            }
        }
        __builtin_amdgcn_s_setprio(0);

        __syncthreads();   // drains DMA vmcnt + all LDS reads before buffer swap
        buf ^= 1;
    }

    // ---- epilogue: O = acc / l_i  (l for q-row q4*4+r lives at lane q4*4+r)
    #pragma unroll
    for (int h = 0; h < 2; ++h) {
        float inv[4];
        #pragma unroll
        for (int r = 0; r < 4; ++r)
            inv[r] = __builtin_amdgcn_rcpf(__shfl(l_i[h], q4 * 4 + r));
        #pragma unroll
        for (int t = 0; t < 8; ++t) {
            #pragma unroll
            for (int r = 0; r < 4; ++r) {
                const int rg = row0[h] + q4 * 4 + r;
                O[hb + (size_t)rg * DIM + t * 16 + l15] = o_acc[h][t][r] * inv[r];
            }
        }
    }
}

// ============================================================================
// Fallback: used only if ws_size < 64 MB. (R1 lineage, proven)
// ============================================================================
#define QROWS_FB 128
__global__ __launch_bounds__(256, 2)
void fa_fwd_fb(const float* __restrict__ Q, const float* __restrict__ K,
               const float* __restrict__ V, float* __restrict__ O)
{
    const int qt = gridDim.x - 1 - blockIdx.x;
    const int qb = qt * QROWS_FB;
    const size_t hb = (size_t)blockIdx.y * SEQ * DIM;
    const int tid  = threadIdx.x;
    const int w    = tid >> 6;
    const int lane = tid & 63;
    const int l15  = lane & 15;
    const int q4   = lane >> 4;

    __shared__ ushort kblob[2][16 * 64 * 8];
    __shared__ ushort vblob[2][16 * 64 * 8];
    __shared__ ushort pblob[4][2][64 * 8];

    const int row0[2] = { qb + w * 16, qb + 64 + w * 16 };
    short8 qf[2][4];
    #pragma unroll
    for (int h = 0; h < 2; ++h) {
        const float* qp = Q + hb + (size_t)(row0[h] + l15) * DIM + q4 * 8;
        #pragma unroll
        for (int kk = 0; kk < 4; ++kk) {
            float4 a = *(const float4*)(qp + kk * 32);
            float4 b = *(const float4*)(qp + kk * 32 + 4);
            union { short8 s; uint32_t u[4]; } u_;
            u_.u[0] = pack_bf16x2(a.x, a.y);
            u_.u[1] = pack_bf16x2(a.z, a.w);
            u_.u[2] = pack_bf16x2(b.x, b.y);
            u_.u[3] = pack_bf16x2(b.z, b.w);
            qf[h][kk] = u_.s;
        }
    }
    floatx4 o_acc[2][8];
    float m_i[2][4], l_i[2][4];
    #pragma unroll
    for (int h = 0; h < 2; ++h) {
        #pragma unroll
        for (int t = 0; t < 8; ++t) o_acc[h][t] = (floatx4){0.f, 0.f, 0.f, 0.f};
        #pragma unroll
        for (int r = 0; r < 4; ++r) { m_i[h][r] = -1e38f; l_i[h][r] = 0.f; }
    }
    float4 kr[4][2];
    float  vr[4][8];
    auto issue_k = [&](int kb) {
        #pragma unroll
        for (int p = 0; p < 4; ++p) {
            const int g = p * 4 + w;
            const float* ks = K + hb + (size_t)(kb + (g >> 2) * 16 + l15) * DIM + (g & 3) * 32 + q4 * 8;
            kr[p][0] = *(const float4*)ks;
            kr[p][1] = *(const float4*)(ks + 4);
        }
    };
    auto commit_k = [&](int buf) {
        #pragma unroll
        for (int p = 0; p < 4; ++p) {
            const int g = p * 4 + w;
            union { short8 s; uint32_t u[4]; } u_;
            u_.u[0] = pack_bf16x2(kr[p][0].x, kr[p][0].y);
            u_.u[1] = pack_bf16x2(kr[p][0].z, kr[p][0].w);
            u_.u[2] = pack_bf16x2(kr[p][1].x, kr[p][1].y);
            u_.u[3] = pack_bf16x2(kr[p][1].z, kr[p][1].w);
            *(short8*)(&kblob[buf][(g * 64 + lane) * 8]) = u_.s;
        }
    };
    auto issue_v = [&](int kb) {
        #pragma unroll
        for (int p = 0; p < 4; ++p) {
            const int g = p * 4 + w;
            const float* vs = V + hb + (size_t)(kb + (g & 1) * 32 + q4 * 8) * DIM + (g >> 1) * 16 + l15;
            #pragma unroll
            for (int j = 0; j < 8; ++j) vr[p][j] = vs[j * DIM];
        }
    };
    auto commit_v = [&](int buf) {
        #pragma unroll
        for (int p = 0; p < 4; ++p) {
            const int g = p * 4 + w;
            union { short8 s; uint32_t u[4]; } u_;
            u_.u[0] = pack_bf16x2(vr[p][0], vr[p][1]);
            u_.u[1] = pack_bf16x2(vr[p][2], vr[p][3]);
            u_.u[2] = pack_bf16x2(vr[p][4], vr[p][5]);
            u_.u[3] = pack_bf16x2(vr[p][6], vr[p][7]);
            *(short8*)(&vblob[buf][(g * 64 + lane) * 8]) = u_.s;
        }
    };
    issue_k(0); commit_k(0);
    issue_v(0); commit_v(0);
    __syncthreads();
    const int kend = qb + QROWS_FB;
    int buf = 0;
    for (int kb = 0; kb < kend; kb += BK) {
        const bool more = (kb + BK) < kend;
        if (more) issue_k(kb + BK);
        const bool act0 = kb <= row0[0] + 15;
        floatx4 sc[2][4];
        #pragma unroll
        for (int h = 0; h < 2; ++h)
            #pragma unroll
            for (int c = 0; c < 4; ++c) sc[h][c] = (floatx4){0.f,0.f,0.f,0.f};
        #pragma unroll
        for (int kk = 0; kk < 4; ++kk) {
            #pragma unroll
            for (int c = 0; c < 4; ++c) {
                short8 b = *(const short8*)(&kblob[buf][((c * 4 + kk) * 64 + lane) * 8]);
                if (act0) sc[0][c] = __builtin_amdgcn_mfma_f32_16x16x32_bf16(qf[0][kk], b, sc[0][c], 0, 0, 0);
                sc[1][c] = __builtin_amdgcn_mfma_f32_16x16x32_bf16(qf[1][kk], b, sc[1][c], 0, 0, 0);
            }
        }
        if (more) { commit_k(buf ^ 1); issue_v(kb + BK); }
        short8 pf[2][2];
        #pragma unroll
        for (int h = 0; h < 2; ++h) {
            if (h == 0 && !act0) continue;
            float mx[4];
            #pragma unroll
            for (int r = 0; r < 4; ++r) {
                const int rg = row0[h] + q4 * 4 + r;
                float m = -1e38f;
                #pragma unroll
                for (int c = 0; c < 4; ++c) {
                    float a = sc[h][c][r] * QK_SCALE_LOG2E;
                    a = (kb + c * 16 + l15 <= rg) ? a : -1e38f;
                    sc[h][c][r] = a;
                    m = fmaxf(m, a);
                }
                mx[r] = m;
            }
            #pragma unroll
            for (int r = 0; r < 4; ++r) {
                float v = mx[r];
                v = fmaxf(v, __shfl_xor(v, 1));
                v = fmaxf(v, __shfl_xor(v, 2));
                v = fmaxf(v, __shfl_xor(v, 4));
                v = fmaxf(v, __shfl_xor(v, 8));
                mx[r] = v;
            }
            float alpha[4], rsum[4];
            #pragma unroll
            for (int r = 0; r < 4; ++r) {
                const float mnew = fmaxf(m_i[h][r], mx[r]);
                alpha[r] = __builtin_amdgcn_exp2f(m_i[h][r] - mnew);
                m_i[h][r] = mnew;
                float s = 0.f;
                #pragma unroll
                for (int c = 0; c < 4; ++c) {
                    const float p = __builtin_amdgcn_exp2f(sc[h][c][r] - mnew);
                    sc[h][c][r] = p;
                    s += p;
                }
                rsum[r] = s;
            }
            #pragma unroll
            for (int r = 0; r < 4; ++r) {
                float v = rsum[r];
                v += __shfl_xor(v, 1);
                v += __shfl_xor(v, 2);
                v += __shfl_xor(v, 4);
                v += __shfl_xor(v, 8);
                l_i[h][r] = l_i[h][r] * alpha[r] + v;
            }
            #pragma unroll
            for (int c = 0; c < 4; ++c) {
                ushort* pw = pblob[w][c >> 1];
                const int wo = ((c & 1) * 2 + (l15 >> 3)) * 16;
                #pragma unroll
                for (int r = 0; r < 4; ++r)
                    pw[(wo + q4 * 4 + r) * 8 + (l15 & 7)] = f2bf_rn(sc[h][c][r]);
            }
            asm volatile("s_waitcnt lgkmcnt(0)" ::: "memory");
            pf[h][0] = *(const short8*)(&pblob[w][0][lane * 8]);
            pf[h][1] = *(const short8*)(&pblob[w][1][lane * 8]);
            #pragma unroll
            for (int t = 0; t < 8; ++t)
                #pragma unroll
                for (int r = 0; r < 4; ++r)
                    o_acc[h][t][r] *= alpha[r];
        }
        #pragma unroll
        for (int t = 0; t < 8; ++t) {
            #pragma unroll
            for (int kc = 0; kc < 2; ++kc) {
                short8 vf = *(const short8*)(&vblob[buf][((t * 2 + kc) * 64 + lane) * 8]);
                if (act0) o_acc[0][t] = __builtin_amdgcn_mfma_f32_16x16x32_bf16(pf[0][kc], vf, o_acc[0][t], 0, 0, 0);
                o_acc[1][t] = __builtin_amdgcn_mfma_f32_16x16x32_bf16(pf[1][kc], vf, o_acc[1][t], 0, 0, 0);
            }
        }
        if (more) commit_v(buf ^ 1);
        __syncthreads();
        buf ^= 1;
    }
    #pragma unroll
    for (int h = 0; h < 2; ++h) {
        float inv[4];
        #pragma unroll
        for (int r = 0; r < 4; ++r) inv[r] = __builtin_amdgcn_rcpf(l_i[h][r]);
        #pragma unroll
        for (int t = 0; t < 8; ++t) {
            #pragma unroll
            for (int r = 0; r < 4; ++r) {
                const int rg = row0[h] + q4 * 4 + r;
                O[hb + (size_t)rg * DIM + t * 16 + l15] = o_acc[h][t][r] * inv[r];
            }
        }
    }
}

extern "C" void kernel_launch(void* const* d_in, const int* in_sizes, int n_in,
                              void* d_out, int out_size, void* d_ws, size_t ws_size,
                              hipStream_t stream) {
    const float* q = (const float*)d_in[0];
    const float* k = (const float*)d_in[1];
    const float* v = (const float*)d_in[2];
    float* o = (float*)d_out;

    const size_t BLOB_BYTES = (size_t)BATCH * HEADS * SEQ * DIM * 2;  // 32 MB each
    if (ws_size >= 2 * BLOB_BYTES) {
        ushort* Kb = (ushort*)d_ws;
        ushort* Vb = (ushort*)((char*)d_ws + BLOB_BYTES);
        convert_kv<<<dim3(BATCH * HEADS * KT_TILES), dim3(256), 0, stream>>>(k, v, Kb, Vb);
        dim3 grid(SEQ / QROWS, BATCH * HEADS);
        fa_fwd<<<grid, dim3(256), 0, stream>>>(q, Kb, Vb, o);
    } else {
        dim3 grid(SEQ / QROWS_FB, BATCH * HEADS);
        fa_fwd_fb<<<grid, dim3(256), 0, stream>>>(q, k, v, o);
    }
}